// Round 5
// baseline (83.027 us; speedup 1.0000x reference)
//
#include <hip/hip_runtime.h>

typedef float v2f __attribute__((ext_vector_type(2)));

// Bernstein->monomial basis change, degree 5, with input remap t=(x+1)/2 folded in:
// B_i((x+1)/2) = sum_d Mb[i][d] * x^d   (entries exact in fp32: integer/32)
__device__ __constant__ float Mb[6][6] = {
    { 0.03125f, -0.15625f,  0.3125f, -0.3125f,  0.15625f, -0.03125f},
    { 0.15625f, -0.46875f,  0.3125f,  0.3125f, -0.46875f,  0.15625f},
    { 0.3125f,  -0.3125f,  -0.625f,   0.625f,   0.3125f,  -0.3125f },
    { 0.3125f,   0.3125f,  -0.625f,  -0.625f,   0.3125f,   0.3125f },
    { 0.15625f,  0.46875f,  0.3125f, -0.3125f, -0.46875f, -0.15625f},
    { 0.03125f,  0.15625f,  0.3125f,  0.3125f,  0.15625f,  0.03125f},
};

// One block: p[3][6][6][6] (Bernstein) -> A[3][6][6][6] monomial coeffs in raw
// x,y,z in [-1,1], with the q' = 2q-1 output transform folded in.
__global__ void ffd_coeff(const float* __restrict__ p, float* __restrict__ A)
{
    __shared__ float b0[648];
    __shared__ float b1[648];
    const int t = threadIdx.x;

    for (int m = t; m < 648; m += 256) b0[m] = p[m];
    __syncthreads();

    for (int m = t; m < 648; m += 256) {       // k -> dk
        const int dk = m % 6;
        const int base = (m / 6) * 6;
        float s = 0.f;
        #pragma unroll
        for (int k = 0; k < 6; ++k) s = fmaf(b0[base + k], Mb[k][dk], s);
        b1[m] = s;
    }
    __syncthreads();

    for (int m = t; m < 648; m += 256) {       // j -> dj
        const int dk = m % 6;
        const int dj = (m / 6) % 6;
        const int ci = m / 36;
        float s = 0.f;
        #pragma unroll
        for (int j = 0; j < 6; ++j) s = fmaf(b1[(ci * 6 + j) * 6 + dk], Mb[j][dj], s);
        b0[m] = s;
    }
    __syncthreads();

    for (int m = t; m < 648; m += 256) {       // i -> di, fold 2q-1
        const int dk = m % 6;
        const int dj = (m / 6) % 6;
        const int di = (m / 36) % 6;
        const int c  = m / 216;
        float s = 0.f;
        #pragma unroll
        for (int i = 0; i < 6; ++i) s = fmaf(b0[((c * 6 + i) * 6 + dj) * 6 + dk], Mb[i][di], s);
        s *= 2.0f;
        if (di == 0 && dj == 0 && dk == 0) s -= 1.0f;
        A[m] = s;
    }
}

// Eval: 8 vertices/thread as 4 packed fp32 pairs. Horner chains expressed as
// <2 x float> fma -> v_pk_fma_f32 (VOP3P, 2 fp32 FMA/inst/lane) halves the
// VALU instruction count vs scalar v_fma_f32 (645 FMA/vertex is the algebraic
// floor; packing is the only remaining instruction-count lever).
// Coefficients: wave-uniform SMEM loads (SGPR), broadcast into both packed
// halves. Dynamic 18-iteration (c,i) loop keeps live set bounded.
__global__ __launch_bounds__(256) void ffd_eval(const float* __restrict__ verts,
                                                const float* __restrict__ A,
                                                float* __restrict__ out, int N)
{
    const int t = blockIdx.x * blockDim.x + threadIdx.x;
    const long long v0 = (long long)t * 8;
    if (v0 >= N) return;

    float xf[8], yf[8], zf[8];
    const bool full = (v0 + 8 <= N);
    if (full) {
        const float4* vp = (const float4*)(verts + v0 * 3);  // 96B offset -> 16B aligned
        float4 f[6];
        #pragma unroll
        for (int r = 0; r < 6; ++r) f[r] = vp[r];
        const float* ff = (const float*)f;
        #pragma unroll
        for (int v = 0; v < 8; ++v) {
            xf[v] = ff[v * 3 + 0]; yf[v] = ff[v * 3 + 1]; zf[v] = ff[v * 3 + 2];
        }
    } else {
        #pragma unroll
        for (int v = 0; v < 8; ++v) {
            long long n = v0 + v; if (n >= N) n = N - 1;
            xf[v] = verts[n * 3 + 0]; yf[v] = verts[n * 3 + 1]; zf[v] = verts[n * 3 + 2];
        }
    }

    v2f x2[4], y2[4], z2[4];
    #pragma unroll
    for (int r = 0; r < 4; ++r) {
        x2[r] = (v2f){xf[2 * r], xf[2 * r + 1]};
        y2[r] = (v2f){yf[2 * r], yf[2 * r + 1]};
        z2[r] = (v2f){zf[2 * r], zf[2 * r + 1]};
    }

    float res[24];
    #pragma unroll 1
    for (int c = 0; c < 3; ++c) {
        v2f q[4];
        #pragma unroll 1
        for (int ii = 0; ii < 6; ++ii) {
            const int i = 5 - ii;
            // 36 uniform coefficients for this (c,i); 144B-aligned SMEM loads.
            const float* __restrict__ Ak = A + (c * 6 + i) * 36;
            v2f tj[4];
            #pragma unroll
            for (int jj = 0; jj < 6; ++jj) {
                const int j = 5 - jj;
                const float a0 = Ak[j * 6 + 0], a1 = Ak[j * 6 + 1],
                            a2 = Ak[j * 6 + 2], a3 = Ak[j * 6 + 3],
                            a4 = Ak[j * 6 + 4], a5 = Ak[j * 6 + 5];
                const v2f A0 = {a0, a0}, A1 = {a1, a1}, A2 = {a2, a2},
                          A3 = {a3, a3}, A4 = {a4, a4}, A5 = {a5, a5};
                #pragma unroll
                for (int v = 0; v < 4; ++v) {
                    v2f s = __builtin_elementwise_fma(A5, z2[v], A4);
                    s = __builtin_elementwise_fma(s, z2[v], A3);
                    s = __builtin_elementwise_fma(s, z2[v], A2);
                    s = __builtin_elementwise_fma(s, z2[v], A1);
                    s = __builtin_elementwise_fma(s, z2[v], A0);
                    tj[v] = (jj == 0) ? s : __builtin_elementwise_fma(tj[v], y2[v], s);
                }
            }
            #pragma unroll
            for (int v = 0; v < 4; ++v)
                q[v] = (ii == 0) ? tj[v] : __builtin_elementwise_fma(q[v], x2[v], tj[v]);
        }
        #pragma unroll
        for (int v = 0; v < 4; ++v) {
            res[(2 * v) * 3 + c]     = q[v].x;
            res[(2 * v + 1) * 3 + c] = q[v].y;
        }
    }

    if (full) {
        float4* op = (float4*)(out + v0 * 3);
        #pragma unroll
        for (int r = 0; r < 6; ++r)
            op[r] = make_float4(res[r * 4 + 0], res[r * 4 + 1],
                                res[r * 4 + 2], res[r * 4 + 3]);
    } else {
        #pragma unroll
        for (int v = 0; v < 8; ++v) {
            const long long n = v0 + v;
            if (n < N) {
                out[n * 3 + 0] = res[v * 3 + 0];
                out[n * 3 + 1] = res[v * 3 + 1];
                out[n * 3 + 2] = res[v * 3 + 2];
            }
        }
    }
}

extern "C" void kernel_launch(void* const* d_in, const int* in_sizes, int n_in,
                              void* d_out, int out_size, void* d_ws, size_t ws_size,
                              hipStream_t stream)
{
    const float* verts = (const float*)d_in[0];   // [N,3] fp32
    const float* p     = (const float*)d_in[1];   // [3,6,6,6] fp32
    float* out = (float*)d_out;                   // [1,N,3] fp32
    float* A   = (float*)d_ws;                    // 648 floats scratch
    const int N = in_sizes[0] / 3;

    ffd_coeff<<<1, 256, 0, stream>>>(p, A);

    const int threads_needed = (N + 7) / 8;
    const int blocks = (threads_needed + 255) / 256;
    ffd_eval<<<blocks, 256, 0, stream>>>(verts, A, out, N);
}